// Round 1
// baseline (818.489 us; speedup 1.0000x reference)
//
#include <hip/hip_runtime.h>

#define G    256
#define CCH  16
#define HIDN 128
#define TS   16
#define LDSW 19   // padded LDS row stride (18 used), breaks bank aliasing

// ---------------- Kernel 1: conv + MLP + residual ----------------
// out[b,c,h,w] = x + (w2 @ relu(w1 @ y + b1)) * update_mask   (no life mask yet)
// alpha_new[b,h,w] = out[b,3,h,w]   (pristine copy for kernel 2's maxpool)
__global__ __launch_bounds__(256) void nca_compute(
    const float* __restrict__ x, const float* __restrict__ w1,
    const float* __restrict__ b1, const float* __restrict__ w2,
    const float* __restrict__ um, float* __restrict__ out,
    float* __restrict__ alpha_new)
{
    __shared__ float xs[CCH][18 * LDSW];
    const int tx = threadIdx.x, ty = threadIdx.y;
    const int bx = blockIdx.x * TS, by = blockIdx.y * TS, b = blockIdx.z;
    const int tid = ty * TS + tx;

    // stage 18x18 halo tile of all 16 channels into LDS
    const float* xb = x + (size_t)b * CCH * G * G;
    for (int i = tid; i < CCH * 18 * 18; i += 256) {
        int c   = i / (18 * 18);
        int rem = i % (18 * 18);
        int r   = rem / 18;
        int col = rem % 18;
        int gy = by + r - 1, gx = bx + col - 1;
        float v = 0.f;
        if (gy >= 0 && gy < G && gx >= 0 && gx < G)
            v = xb[(size_t)c * G * G + (size_t)gy * G + gx];
        xs[c][r * LDSW + col] = v;
    }
    __syncthreads();

    // perception vector y[48]: per channel [identity, sobel_x/8, sobel_y/8]
    float y[48];
    #pragma unroll
    for (int c = 0; c < CCH; c++) {
        float a00 = xs[c][(ty    ) * LDSW + tx    ];
        float a01 = xs[c][(ty    ) * LDSW + tx + 1];
        float a02 = xs[c][(ty    ) * LDSW + tx + 2];
        float a10 = xs[c][(ty + 1) * LDSW + tx    ];
        float a11 = xs[c][(ty + 1) * LDSW + tx + 1];
        float a12 = xs[c][(ty + 1) * LDSW + tx + 2];
        float a20 = xs[c][(ty + 2) * LDSW + tx    ];
        float a21 = xs[c][(ty + 2) * LDSW + tx + 1];
        float a22 = xs[c][(ty + 2) * LDSW + tx + 2];
        y[3 * c]     = a11;
        y[3 * c + 1] = ((a02 - a00) + 2.f * (a12 - a10) + (a22 - a20)) * 0.125f;
        y[3 * c + 2] = ((a20 - a00) + 2.f * (a21 - a01) + (a22 - a02)) * 0.125f;
    }

    float acc[CCH];
    #pragma unroll
    for (int c = 0; c < CCH; c++) acc[c] = 0.f;

    // MLP: weights are wave-uniform -> scalar-cache loads feeding FMA s-operand
    for (int k = 0; k < HIDN; k++) {
        const float* w1r = w1 + k * 48;
        float h0 = b1[k], h1 = 0.f, h2 = 0.f, h3 = 0.f;  // break dep chain 4-way
        #pragma unroll
        for (int c = 0; c < 48; c += 4) {
            h0 = fmaf(w1r[c    ], y[c    ], h0);
            h1 = fmaf(w1r[c + 1], y[c + 1], h1);
            h2 = fmaf(w1r[c + 2], y[c + 2], h2);
            h3 = fmaf(w1r[c + 3], y[c + 3], h3);
        }
        float hk = fmaxf((h0 + h1) + (h2 + h3), 0.f);
        #pragma unroll
        for (int c = 0; c < CCH; c++)
            acc[c] = fmaf(w2[c * HIDN + k], hk, acc[c]);
    }

    const int gy = by + ty, gx = bx + tx;
    const float m = um[(size_t)b * G * G + (size_t)gy * G + gx];
    const size_t pix   = (size_t)gy * G + gx;
    const size_t obase = (size_t)b * CCH * G * G + pix;
    #pragma unroll
    for (int c = 0; c < CCH; c++) {
        float xn = xs[c][(ty + 1) * LDSW + tx + 1] + acc[c] * m;
        out[obase + (size_t)c * G * G] = xn;
        if (c == 3) alpha_new[(size_t)b * G * G + pix] = xn;
    }
}

// ---------------- Kernel 2: alive mask ----------------
// life = (maxpool3x3(x.alpha) > 0.1) & (maxpool3x3(x_new.alpha) > 0.1)
// zero out the (~0.6%) dead pixels; live pixels already hold x_new.
__global__ __launch_bounds__(256) void nca_mask(
    const float* __restrict__ x, const float* __restrict__ alpha_new,
    float* __restrict__ out)
{
    __shared__ float pa[18 * LDSW];
    __shared__ float na[18 * LDSW];
    const int tx = threadIdx.x, ty = threadIdx.y;
    const int bx = blockIdx.x * TS, by = blockIdx.y * TS, b = blockIdx.z;
    const int tid = ty * TS + tx;

    const float* xa = x + (size_t)b * CCH * G * G + (size_t)3 * G * G;
    const float* nb = alpha_new + (size_t)b * G * G;
    for (int i = tid; i < 18 * 18; i += 256) {
        int r = i / 18, col = i % 18;
        int gy = by + r - 1, gx = bx + col - 1;
        float vp = -1e30f, vn = -1e30f;
        if (gy >= 0 && gy < G && gx >= 0 && gx < G) {
            vp = xa[(size_t)gy * G + gx];
            vn = nb[(size_t)gy * G + gx];
        }
        pa[r * LDSW + col] = vp;
        na[r * LDSW + col] = vn;
    }
    __syncthreads();

    float mp = -1e30f, mn = -1e30f;
    #pragma unroll
    for (int dy = 0; dy < 3; dy++) {
        #pragma unroll
        for (int dx = 0; dx < 3; dx++) {
            mp = fmaxf(mp, pa[(ty + dy) * LDSW + tx + dx]);
            mn = fmaxf(mn, na[(ty + dy) * LDSW + tx + dx]);
        }
    }
    const bool life = (mp > 0.1f) && (mn > 0.1f);
    if (!life) {
        const size_t obase = (size_t)b * CCH * G * G + (size_t)(by + ty) * G + (bx + tx);
        #pragma unroll
        for (int c = 0; c < CCH; c++)
            out[obase + (size_t)c * G * G] = 0.f;
    }
}

extern "C" void kernel_launch(void* const* d_in, const int* in_sizes, int n_in,
                              void* d_out, int out_size, void* d_ws, size_t ws_size,
                              hipStream_t stream) {
    const float* x  = (const float*)d_in[0];
    const float* w1 = (const float*)d_in[1];
    const float* b1 = (const float*)d_in[2];
    const float* w2 = (const float*)d_in[3];
    const float* um = (const float*)d_in[4];
    float* out = (float*)d_out;
    float* alpha_new = (float*)d_ws;   // B*G*G floats = 8.4 MB scratch

    dim3 grid(G / TS, G / TS, 32);
    dim3 block(TS, TS);
    nca_compute<<<grid, block, 0, stream>>>(x, w1, b1, w2, um, out, alpha_new);
    nca_mask<<<grid, block, 0, stream>>>(x, alpha_new, out);
}